// Round 3
// baseline (131.106 us; speedup 1.0000x reference)
//
#include <hip/hip_runtime.h>
#include <hip/hip_bf16.h>
#include <math.h>

#define NN 4096
#define BM 128
#define BK 32
#define LDST 40              // LDS row stride in bf16 (80 B: 16B-aligned, read-conflict-free)
#define NB 32
#define NUPPER 528
#define NLOWER 496
#define NWORK 1000           // split-K work items: sum over d of (32-d)*ceil((d+1)/8)
#define NSLOTS 472           // partial slots: sum over d of (32-d)*(ceil((d+1)/8)-1)
#define NMERGE 300           // tiles with d>=8 (S>=2)
#define TILE_ELEMS (128*128)

typedef __bf16 v8bf __attribute__((ext_vector_type(8)));
typedef __bf16 v4bf __attribute__((ext_vector_type(4)));
typedef float  v4f  __attribute__((ext_vector_type(4)));

__global__ __launch_bounds__(256)
void trimm_main(const float* __restrict__ A,
                const float* __restrict__ B,
                float* __restrict__ C,
                float* __restrict__ part,
                int split, int nwork) {
    const int id = blockIdx.x;
    const int t  = threadIdx.x;

    if (id >= nwork) {
        // -------- zero-fill a strictly-lower tile (bi > bj) --------
        int z = id - nwork;
        int bi = (int)((1.0 + sqrt(1.0 + 8.0 * (double)z)) * 0.5);
        while (bi * (bi - 1) / 2 > z) --bi;
        while ((bi + 1) * bi / 2 <= z) ++bi;
        int bj = z - bi * (bi - 1) / 2;
        const long brow = (long)bi * BM;
        const long bcol = (long)bj * BM;
        const float4 zv = make_float4(0.f, 0.f, 0.f, 0.f);
        #pragma unroll
        for (int i = 0; i < 16; ++i) {
            int s  = i * 256 + t;
            int r  = s >> 5;
            int c4 = (s & 31) << 2;
            *reinterpret_cast<float4*>(&C[(brow + r) * NN + bcol + c4]) = zv;
        }
        return;
    }

    // ---- map id -> (d, bi, chunk c, partial slot), d descending (LPT) ----
    int rem = id, d, S = 1, slotbase = 0;
    for (d = 31;; --d) {
        S = split ? ((d + 8) >> 3) : 1;           // ceil((d+1)/8)
        int cnt = (32 - d) * S;
        if (rem < cnt) break;
        rem -= cnt;
        slotbase += (32 - d) * (S - 1);
    }
    const int bi = rem / S;
    const int c  = rem % S;
    const int bj = bi + d;

    const long brow = (long)bi * BM;
    const long bcol = (long)bj * BM;

    const int  units = split ? min(8, (d + 1) - c * 8) : (d + 1);
    const int  nt    = units * (BM / BK);
    const long kst   = brow + (long)c * 1024;

    float* outp;
    int    ostride;
    if (c == 0) { outp = C + brow * NN + bcol; ostride = NN; }
    else {
        long slot = slotbase + (long)bi * (S - 1) + (c - 1);
        outp = part + slot * TILE_ELEMS; ostride = BM;
    }

    __shared__ __bf16 As[2][BM][LDST];
    __shared__ __bf16 Bs[2][BM][LDST];   // transposed: Bs[buf][n][k]

    const int lane = t & 63;
    const int wave = t >> 6;
    const int wm = (wave >> 1) * 64;
    const int wn = (wave & 1) * 64;
    const int l15 = lane & 15;
    const int g   = lane >> 4;

    const int arow = t >> 3;
    const int akc  = (t & 7) << 2;
    const int bn   = t & 31;
    const int bkc  = (t >> 5) << 2;

    v4f acc[4][4];
    #pragma unroll
    for (int mf = 0; mf < 4; ++mf)
        #pragma unroll
        for (int nf = 0; nf < 4; ++nf)
            acc[mf][nf] = (v4f){0.f, 0.f, 0.f, 0.f};

    float4 aR[4];
    float  bR[16];

    #define ISSUE_LOADS(KT)                                                   \
        {                                                                     \
            _Pragma("unroll")                                                 \
            for (int i = 0; i < 4; ++i)                                       \
                aR[i] = *reinterpret_cast<const float4*>(                     \
                    &A[(brow + arow + 32 * i) * NN + (KT) + akc]);            \
            _Pragma("unroll")                                                 \
            for (int jj = 0; jj < 4; ++jj) {                                  \
                const float* Brow = B + ((KT) + bkc + jj) * NN + bcol + bn;   \
                _Pragma("unroll")                                             \
                for (int j = 0; j < 4; ++j) bR[jj * 4 + j] = Brow[32 * j];    \
            }                                                                 \
        }

    #define WRITE_LDS(BUF)                                                    \
        {                                                                     \
            _Pragma("unroll")                                                 \
            for (int i = 0; i < 4; ++i) {                                     \
                v4bf pk;                                                      \
                pk[0] = (__bf16)aR[i].x; pk[1] = (__bf16)aR[i].y;             \
                pk[2] = (__bf16)aR[i].z; pk[3] = (__bf16)aR[i].w;             \
                *reinterpret_cast<v4bf*>(&As[BUF][arow + 32 * i][akc]) = pk;  \
            }                                                                 \
            _Pragma("unroll")                                                 \
            for (int j = 0; j < 4; ++j) {                                     \
                v4bf pk;                                                      \
                pk[0] = (__bf16)bR[0 * 4 + j]; pk[1] = (__bf16)bR[1 * 4 + j]; \
                pk[2] = (__bf16)bR[2 * 4 + j]; pk[3] = (__bf16)bR[3 * 4 + j]; \
                *reinterpret_cast<v4bf*>(&Bs[BUF][bn + 32 * j][bkc]) = pk;    \
            }                                                                 \
        }

    ISSUE_LOADS(kst);
    WRITE_LDS(0);
    __syncthreads();

    int cur = 0;
    for (int tk = 0; tk < nt; ++tk) {
        const bool more = (tk + 1 < nt);
        if (more) { ISSUE_LOADS(kst + (long)(tk + 1) * BK); }

        v8bf af[4], bfr[4];
        #pragma unroll
        for (int mf = 0; mf < 4; ++mf)
            af[mf] = *reinterpret_cast<const v8bf*>(&As[cur][wm + mf * 16 + l15][g * 8]);
        #pragma unroll
        for (int nf = 0; nf < 4; ++nf)
            bfr[nf] = *reinterpret_cast<const v8bf*>(&Bs[cur][wn + nf * 16 + l15][g * 8]);

        #pragma unroll
        for (int mf = 0; mf < 4; ++mf)
            #pragma unroll
            for (int nf = 0; nf < 4; ++nf)
                acc[mf][nf] = __builtin_amdgcn_mfma_f32_16x16x32_bf16(
                    af[mf], bfr[nf], acc[mf][nf], 0, 0, 0);

        if (more) { WRITE_LDS(cur ^ 1); }
        __syncthreads();
        cur ^= 1;
    }

    // epilogue: C/D layout col=lane&15, row=(lane>>4)*4+reg
    #pragma unroll
    for (int mf = 0; mf < 4; ++mf) {
        #pragma unroll
        for (int nf = 0; nf < 4; ++nf) {
            int row = wm + mf * 16 + g * 4;
            int col = wn + nf * 16 + l15;
            #pragma unroll
            for (int r = 0; r < 4; ++r)
                outp[(long)(row + r) * ostride + col] = acc[mf][nf][r];
        }
    }
    #undef ISSUE_LOADS
    #undef WRITE_LDS
}

__global__ __launch_bounds__(256)
void trimm_merge(float* __restrict__ C, const float* __restrict__ part) {
    int rem = blockIdx.x;
    const int t = threadIdx.x;
    int d, S = 1, slotbase = 0;
    for (d = 31;; --d) {
        S = (d + 8) >> 3;
        int cnt = 32 - d;
        if (rem < cnt) break;
        rem -= cnt;
        slotbase += cnt * (S - 1);
    }
    const int bi = rem;
    const int ns = S - 1;                 // 1..3 partials to add
    const long brow = (long)bi * BM;
    const long bcol = (long)(bi + d) * BM;
    const long slot0 = slotbase + (long)bi * ns;

    #pragma unroll
    for (int i = 0; i < 16; ++i) {
        int s  = i * 256 + t;
        int r  = s >> 5;
        int c4 = (s & 31) << 2;
        float4 v = *reinterpret_cast<const float4*>(&C[(brow + r) * NN + bcol + c4]);
        for (int q = 0; q < ns; ++q) {
            const float4 p = *reinterpret_cast<const float4*>(
                &part[(slot0 + q) * TILE_ELEMS + r * BM + c4]);
            v.x += p.x; v.y += p.y; v.z += p.z; v.w += p.w;
        }
        *reinterpret_cast<float4*>(&C[(brow + r) * NN + bcol + c4]) = v;
    }
}

extern "C" void kernel_launch(void* const* d_in, const int* in_sizes, int n_in,
                              void* d_out, int out_size, void* d_ws, size_t ws_size,
                              hipStream_t stream) {
    const float* A = (const float*)d_in[0];
    const float* B = (const float*)d_in[1];
    float* C = (float*)d_out;
    float* part = (float*)d_ws;

    const size_t need = (size_t)NSLOTS * TILE_ELEMS * sizeof(float);  // ~31 MB
    const int split = (ws_size >= need) ? 1 : 0;
    const int nwork = split ? NWORK : NUPPER;

    trimm_main<<<dim3(nwork + NLOWER), 256, 0, stream>>>(A, B, C, part, split, nwork);
    if (split)
        trimm_merge<<<dim3(NMERGE), 256, 0, stream>>>(C, part);
}

// Round 4
// 85.125 us; speedup vs baseline: 1.5402x; 1.5402x over previous
//
#include <hip/hip_runtime.h>
#include <hip/hip_bf16.h>

#define NN 4096
#define NB 32
#define NUPPER 528
#define NLOWER 496
#define NWORK2 664           // sum over d of (32-d)*S, S=2 for d>=16 else 1
#define NMERGE 136           // tiles with d>=16
#define BLK_ELEMS 16384      // 128*128

typedef __bf16 v8bf __attribute__((ext_vector_type(8)));
typedef __bf16 v4bf __attribute__((ext_vector_type(4)));
typedef float  v4f  __attribute__((ext_vector_type(4)));

typedef __attribute__((address_space(1))) const unsigned int* as1p;
typedef __attribute__((address_space(3))) unsigned int* as3p;
#define GLOAD16(DST_LDS, SRC_G) \
    __builtin_amdgcn_global_load_lds((as1p)(const void*)(SRC_G), (as3p)(void*)(DST_LDS), 16, 0, 0)

// ---------------- prep: bf16-pack A, bf16-transpose-pack B, zero lower C ----
__global__ __launch_bounds__(256)
void trimm_prep(const float* __restrict__ A, const float* __restrict__ B,
                float* __restrict__ C,
                __bf16* __restrict__ Apk, __bf16* __restrict__ Bpk) {
    const int p = blockIdx.x;
    const int t = threadIdx.x;
    __shared__ __bf16 Ls[128][132];

    if (p < NUPPER) {
        // ---- A block (bi, q), row-block-major packing of upper blocks ----
        int bi = 0;
        while ((bi + 1) * 32 - ((bi + 1) * bi) / 2 <= p) ++bi;
        const int base = bi * 32 - (bi * (bi - 1)) / 2;
        const int q = bi + (p - base);
        const float* src = A + (long)bi * 128 * NN + (long)q * 128;
        __bf16* dst = Apk + (long)p * BLK_ELEMS;
        #pragma unroll
        for (int i = 0; i < 16; ++i) {
            int s = i * 256 + t, r = s >> 5, c4 = (s & 31) << 2;
            float4 v = *reinterpret_cast<const float4*>(&src[(long)r * NN + c4]);
            v4bf pk;
            pk[0] = (__bf16)v.x; pk[1] = (__bf16)v.y;
            pk[2] = (__bf16)v.z; pk[3] = (__bf16)v.w;
            *reinterpret_cast<v4bf*>(&dst[r * 128 + c4]) = pk;
        }
        return;
    }
    if (p < 2 * NUPPER) {
        // ---- B block (q, bj) -> Bpk[bj-row][k] transposed, idx bj*(bj+1)/2+q
        const int p2 = p - NUPPER;
        int bj = 0;
        while (((bj + 1) * (bj + 2)) / 2 <= p2) ++bj;
        const int q = p2 - (bj * (bj + 1)) / 2;
        const float* src = B + (long)q * 128 * NN + (long)bj * 128;
        __bf16* dst = Bpk + (long)p2 * BLK_ELEMS;
        #pragma unroll
        for (int i = 0; i < 16; ++i) {
            int s = i * 256 + t, k = s >> 5, n4 = (s & 31) << 2;
            float4 v = *reinterpret_cast<const float4*>(&src[(long)k * NN + n4]);
            Ls[k][n4 + 0] = (__bf16)v.x; Ls[k][n4 + 1] = (__bf16)v.y;
            Ls[k][n4 + 2] = (__bf16)v.z; Ls[k][n4 + 3] = (__bf16)v.w;
        }
        __syncthreads();
        #pragma unroll
        for (int i = 0; i < 8; ++i) {
            int n = i * 16 + (t >> 4), k0 = (t & 15) << 3;
            v8bf o;
            #pragma unroll
            for (int j = 0; j < 8; ++j) o[j] = Ls[k0 + j][n];
            *reinterpret_cast<v8bf*>(&dst[n * 128 + k0]) = o;
        }
        return;
    }
    // ---- zero-fill strictly-lower C tile ----
    const int z = p - 2 * NUPPER;
    int bi = 1;
    while (((bi + 1) * bi) / 2 <= z) ++bi;
    const int bj = z - (bi * (bi - 1)) / 2;
    const long brow = (long)bi * 128, bcol = (long)bj * 128;
    const float4 zv = make_float4(0.f, 0.f, 0.f, 0.f);
    #pragma unroll
    for (int i = 0; i < 16; ++i) {
        int s = i * 256 + t, r = s >> 5, c4 = (s & 31) << 2;
        *reinterpret_cast<float4*>(&C[(brow + r) * NN + bcol + c4]) = zv;
    }
}

// ---------------- main MFMA kernel: 128^2 tile, BK=64, gload_lds + swizzle --
__global__ __launch_bounds__(256, 4)
void trimm_mm(const __bf16* __restrict__ Apk, const __bf16* __restrict__ Bpk,
              float* __restrict__ C, float* __restrict__ part) {
    const int id = blockIdx.x;
    const int t  = threadIdx.x;

    // map id -> (d desc, bi, chunk c); slot base for partials
    int rem = id, d, S, sb = 0;
    for (d = 31;; --d) {
        S = (d >= 16) ? 2 : 1;
        int cnt = (32 - d) * S;
        if (rem < cnt) break;
        rem -= cnt;
        if (d >= 16) sb += (32 - d);
    }
    const int bi = rem / S, c = rem % S;
    const int bj = bi + d;
    const int U  = d + 1;
    const int u0 = (S == 2) ? ((U + 1) >> 1) : U;
    const int units = (c == 0) ? u0 : (U - u0);
    const int nt = units * 2;                      // BK=64 steps
    const int q0 = bi + ((c == 0) ? 0 : u0);       // first 128-k block
    const int abase0 = bi * 32 - (bi * (bi - 1)) / 2 - bi;  // A idx = abase0+q
    const int bbase0 = (bj * (bj + 1)) / 2;                 // B idx = bbase0+q

    float* outp; int ostride;
    if (c == 0) { outp = C + (long)bi * 128 * NN + (long)bj * 128; ostride = NN; }
    else        { outp = part + (long)(sb + bi) * BLK_ELEMS;       ostride = 128; }

    __shared__ __bf16 AsF[8192];   // logical [128 rows][64 k], XOR-swizzled
    __shared__ __bf16 BsF[8192];

    const int lane = t & 63, wave = t >> 6;
    const int wm = (wave >> 1) << 6, wn = (wave & 1) << 6;
    const int l15 = lane & 15, g = lane >> 4;
    const int swz = (l15 & 7) << 3;                 // elem-index XOR for reads
    const int srow8 = lane >> 3;                    // staging: row within seg
    const int sslot = ((lane & 7) ^ srow8) << 3;    // inverse-swizzled src slot

    v4f acc[4][4];
    #pragma unroll
    for (int mf = 0; mf < 4; ++mf)
        #pragma unroll
        for (int nf = 0; nf < 4; ++nf)
            acc[mf][nf] = (v4f){0.f, 0.f, 0.f, 0.f};

    for (int tk = 0; tk < nt; ++tk) {
        const int q   = q0 + (tk >> 1);
        const int kin = (tk & 1) << 6;
        const long aoff = ((long)(abase0 + q) << 14) + kin + sslot;
        const long boff = ((long)(bbase0 + q) << 14) + kin + sslot;
        #pragma unroll
        for (int i = 0; i < 4; ++i) {
            const int seg = (wave << 2) + i;                   // 16 segs of 8 rows
            const long r128 = (long)(seg * 8 + srow8) << 7;    // row*128 elems
            GLOAD16(AsF + (seg << 9), Apk + aoff + r128);
            GLOAD16(BsF + (seg << 9), Bpk + boff + r128);
        }
        __syncthreads();   // drains vmcnt(0): staged tile visible

        #pragma unroll
        for (int kc = 0; kc < 2; ++kc) {
            v8bf af[4], bfv[4];
            #pragma unroll
            for (int mf = 0; mf < 4; ++mf) {
                int row = wm + mf * 16 + l15;
                af[mf] = *reinterpret_cast<const v8bf*>(
                    &AsF[(row * 64 + kc * 32 + g * 8) ^ swz]);
            }
            #pragma unroll
            for (int nf = 0; nf < 4; ++nf) {
                int row = wn + nf * 16 + l15;
                bfv[nf] = *reinterpret_cast<const v8bf*>(
                    &BsF[(row * 64 + kc * 32 + g * 8) ^ swz]);
            }
            #pragma unroll
            for (int mf = 0; mf < 4; ++mf)
                #pragma unroll
                for (int nf = 0; nf < 4; ++nf)
                    acc[mf][nf] = __builtin_amdgcn_mfma_f32_16x16x32_bf16(
                        af[mf], bfv[nf], acc[mf][nf], 0, 0, 0);
        }
        __syncthreads();   // all reads done before next-stage overwrite
    }

    // epilogue: C/D layout col=lane&15, row=(lane>>4)*4+reg
    #pragma unroll
    for (int mf = 0; mf < 4; ++mf) {
        #pragma unroll
        for (int nf = 0; nf < 4; ++nf) {
            int row = wm + mf * 16 + g * 4;
            int col = wn + nf * 16 + l15;
            #pragma unroll
            for (int r = 0; r < 4; ++r)
                outp[(long)(row + r) * ostride + col] = acc[mf][nf][r];
        }
    }
}

// ---------------- merge: C += partial for tiles with d>=16 ------------------
__global__ __launch_bounds__(256)
void trimm_merge2(float* __restrict__ C, const float* __restrict__ part) {
    int rem = blockIdx.x;
    const int t = threadIdx.x;
    int d, sb = 0;
    for (d = 31;; --d) {
        int cnt = 32 - d;
        if (rem < cnt) break;
        rem -= cnt; sb += cnt;
    }
    const int bi = rem, bj = bi + d;
    const float* pp = part + (long)(sb + bi) * BLK_ELEMS;
    float* cp = C + (long)bi * 128 * NN + (long)bj * 128;
    #pragma unroll
    for (int i = 0; i < 16; ++i) {
        int s = i * 256 + t, r = s >> 5, c4 = (s & 31) << 2;
        float4 v = *reinterpret_cast<float4*>(&cp[(long)r * NN + c4]);
        float4 w = *reinterpret_cast<const float4*>(&pp[r * 128 + c4]);
        v.x += w.x; v.y += w.y; v.z += w.z; v.w += w.w;
        *reinterpret_cast<float4*>(&cp[(long)r * NN + c4]) = v;
    }
}

// ---------------- fallback (ws too small): round-2 fused kernel -------------
#define LDST 40
__global__ __launch_bounds__(256)
void trimm_fb(const float* __restrict__ A, const float* __restrict__ B,
              float* __restrict__ C) {
    const int id = blockIdx.x, t = threadIdx.x;
    if (id >= NUPPER) {
        int z = id - NUPPER;
        int bi = 1;
        while (((bi + 1) * bi) / 2 <= z) ++bi;
        int bj = z - (bi * (bi - 1)) / 2;
        const long brow = (long)bi * 128, bcol = (long)bj * 128;
        const float4 zv = make_float4(0.f, 0.f, 0.f, 0.f);
        #pragma unroll
        for (int i = 0; i < 16; ++i) {
            int s = i * 256 + t, r = s >> 5, c4 = (s & 31) << 2;
            *reinterpret_cast<float4*>(&C[(brow + r) * NN + bcol + c4]) = zv;
        }
        return;
    }
    int q = (NUPPER - 1) - id;
    int d = 0;
    while (d < 31 && 32 * (d + 1) - (d + 1) * d / 2 <= q) ++d;
    const int bi = q - (32 * d - d * (d - 1) / 2);
    const int bj = bi + d;
    const long brow = (long)bi * 128, bcol = (long)bj * 128;
    __shared__ __bf16 As[128][LDST];
    __shared__ __bf16 Bs[128][LDST];
    const int lane = t & 63, wave = t >> 6;
    const int wm = (wave >> 1) * 64, wn = (wave & 1) * 64;
    const int l15 = lane & 15, g = lane >> 4;
    const int arow = t >> 3, akc = (t & 7) << 2;
    const int bn = t & 31, bkc = (t >> 5) << 2;
    v4f acc[4][4];
    #pragma unroll
    for (int mf = 0; mf < 4; ++mf)
        #pragma unroll
        for (int nf = 0; nf < 4; ++nf) acc[mf][nf] = (v4f){0.f,0.f,0.f,0.f};
    const long k0 = brow;
    const int nt = (d + 1) * 4;
    for (int tk = 0; tk < nt; ++tk) {
        const long kt = k0 + (long)tk * 32;
        #pragma unroll
        for (int i = 0; i < 4; ++i) {
            float4 a4 = *reinterpret_cast<const float4*>(
                &A[(brow + arow + 32 * i) * NN + kt + akc]);
            v4bf pk;
            pk[0]=(__bf16)a4.x; pk[1]=(__bf16)a4.y; pk[2]=(__bf16)a4.z; pk[3]=(__bf16)a4.w;
            *reinterpret_cast<v4bf*>(&As[arow + 32 * i][akc]) = pk;
        }
        {
            float tmp[4][4];
            #pragma unroll
            for (int jj = 0; jj < 4; ++jj) {
                const float* Brow = B + (kt + bkc + jj) * NN + bcol + bn;
                #pragma unroll
                for (int j = 0; j < 4; ++j) tmp[j][jj] = Brow[32 * j];
            }
            #pragma unroll
            for (int j = 0; j < 4; ++j) {
                v4bf pk;
                pk[0]=(__bf16)tmp[j][0]; pk[1]=(__bf16)tmp[j][1];
                pk[2]=(__bf16)tmp[j][2]; pk[3]=(__bf16)tmp[j][3];
                *reinterpret_cast<v4bf*>(&Bs[bn + 32 * j][bkc]) = pk;
            }
        }
        __syncthreads();
        v8bf af[4], bfr[4];
        #pragma unroll
        for (int mf = 0; mf < 4; ++mf)
            af[mf] = *reinterpret_cast<const v8bf*>(&As[wm + mf*16 + l15][g*8]);
        #pragma unroll
        for (int nf = 0; nf < 4; ++nf)
            bfr[nf] = *reinterpret_cast<const v8bf*>(&Bs[wn + nf*16 + l15][g*8]);
        #pragma unroll
        for (int mf = 0; mf < 4; ++mf)
            #pragma unroll
            for (int nf = 0; nf < 4; ++nf)
                acc[mf][nf] = __builtin_amdgcn_mfma_f32_16x16x32_bf16(
                    af[mf], bfr[nf], acc[mf][nf], 0, 0, 0);
        __syncthreads();
    }
    #pragma unroll
    for (int mf = 0; mf < 4; ++mf)
        #pragma unroll
        for (int nf = 0; nf < 4; ++nf) {
            long row = brow + wm + mf * 16 + g * 4;
            long col = bcol + wn + nf * 16 + l15;
            #pragma unroll
            for (int r = 0; r < 4; ++r)
                C[(row + r) * NN + col] = acc[mf][nf][r];
        }
}

extern "C" void kernel_launch(void* const* d_in, const int* in_sizes, int n_in,
                              void* d_out, int out_size, void* d_ws, size_t ws_size,
                              hipStream_t stream) {
    const float* A = (const float*)d_in[0];
    const float* B = (const float*)d_in[1];
    float* C = (float*)d_out;

    const size_t needAB = 2UL * NUPPER * BLK_ELEMS * sizeof(__bf16);  // 33 MB
    const size_t needP  = (size_t)NMERGE * BLK_ELEMS * sizeof(float); // 8.5 MB
    if (ws_size >= needAB + needP) {
        __bf16* Apk = (__bf16*)d_ws;
        __bf16* Bpk = Apk + (size_t)NUPPER * BLK_ELEMS;
        float*  part = (float*)((char*)d_ws + needAB);
        trimm_prep<<<dim3(2 * NUPPER + NLOWER), 256, 0, stream>>>(A, B, C, Apk, Bpk);
        trimm_mm<<<dim3(NWORK2), 256, 0, stream>>>(Apk, Bpk, C, part);
        trimm_merge2<<<dim3(NMERGE), 256, 0, stream>>>(C, part);
    } else {
        trimm_fb<<<dim3(NUPPER + NLOWER), 256, 0, stream>>>(A, B, C);
    }
}